// Round 2
// baseline (19.941 us; speedup 1.0000x reference)
//
#include <hip/hip_runtime.h>

// out[row, :] = weight[ids[row], :]
// rows = B*L = 8192, D = 128 floats = 32 float4 per row.
// 32 lanes cooperate on one row; each lane moves one float4.
// Each thread handles ITEMS=4 independent (row, chunk) work items to get
// MLP=4 on the id-load -> gather-load dependent chain.
#define ITEMS 4

__global__ __launch_bounds__(256) void soft_embedding_gather(
        const int* __restrict__ ids,
        const float4* __restrict__ w4,
        float4* __restrict__ out4,
        int n_items) {                    // n_items = n_rows * 32
    const int gid    = blockIdx.x * blockDim.x + threadIdx.x;
    const int stride = gridDim.x * blockDim.x;

    int   item[ITEMS];
    int   id[ITEMS];
    int   valid = 0;

    #pragma unroll
    for (int t = 0; t < ITEMS; ++t) {
        item[t] = gid + t * stride;
        if (item[t] < n_items) valid = t + 1;
    }

    // Phase 1: all id loads in flight (independent)
    #pragma unroll
    for (int t = 0; t < ITEMS; ++t) {
        if (t < valid) id[t] = ids[item[t] >> 5];
    }

    // Phase 2: all gathers in flight (independent)
    float4 v[ITEMS];
    #pragma unroll
    for (int t = 0; t < ITEMS; ++t) {
        if (t < valid) v[t] = w4[(size_t)id[t] * 32 + (item[t] & 31)];
    }

    // Phase 3: stores
    #pragma unroll
    for (int t = 0; t < ITEMS; ++t) {
        if (t < valid) out4[item[t]] = v[t];
    }
}

extern "C" void kernel_launch(void* const* d_in, const int* in_sizes, int n_in,
                              void* d_out, int out_size, void* d_ws, size_t ws_size,
                              hipStream_t stream) {
    const int*   ids = (const int*)d_in[0];     // [B*L] = 8192
    const float* w   = (const float*)d_in[1];   // [32000, 128]
    float*       out = (float*)d_out;           // [B*L, 128]

    const int n_rows  = in_sizes[0];            // 8192
    const int n_items = n_rows * 32;            // 262144 float4 moves
    const int block   = 256;
    const int grid    = (n_items + block * ITEMS - 1) / (block * ITEMS);  // 256

    soft_embedding_gather<<<grid, block, 0, stream>>>(
        ids, (const float4*)w, (float4*)out, n_items);
}

// Round 3
// 9.733 us; speedup vs baseline: 2.0487x; 2.0487x over previous
//
#include <hip/hip_runtime.h>

// out[row, :] = weight[ids[row], :]
// rows = B*L = 8192, D = 128 floats = 64 float2 per row.
// 64 lanes (one full wave) cooperate on one row; each lane moves one float2.
// Granularity chosen so total waves = 8192 = full chip occupancy (32/CU),
// maximizing independent id->gather latency chains in flight.
__global__ __launch_bounds__(256) void soft_embedding_gather(
        const int* __restrict__ ids,
        const float2* __restrict__ w2,
        float2* __restrict__ out2,
        int n_rows) {
    const int gid = blockIdx.x * blockDim.x + threadIdx.x;
    const int row = gid >> 6;       // 64 threads (one wave) per row
    const int c   = gid & 63;       // float2 index within row (D/2 = 64)
    if (row >= n_rows) return;
    const int id = ids[row];        // wave-uniform -> single broadcast load
    out2[(size_t)row * 64 + c] = w2[(size_t)id * 64 + c];
}

extern "C" void kernel_launch(void* const* d_in, const int* in_sizes, int n_in,
                              void* d_out, int out_size, void* d_ws, size_t ws_size,
                              hipStream_t stream) {
    const int*   ids = (const int*)d_in[0];     // [B*L] = 8192
    const float* w   = (const float*)d_in[1];   // [32000, 128]
    float*       out = (float*)d_out;           // [B*L, 128]

    const int n_rows = in_sizes[0];             // 8192
    const int total  = n_rows * 64;             // threads: 64 per row
    const int block  = 256;
    const int grid   = (total + block - 1) / block;   // 2048 blocks

    soft_embedding_gather<<<grid, block, 0, stream>>>(
        ids, (const float2*)w, (float2*)out, n_rows);
}